// Round 1
// baseline (1477.319 us; speedup 1.0000x reference)
//
#include <hip/hip_runtime.h>
#include <math.h>

#define NB 2048        // batches
#define NS 256         // samples per batch
#define ND 128         // features
#define NCOL 129       // ND+1 (ones column)
#define LDA 132        // padded LDS row stride (floats), keeps float4 alignment
#define BSTRIDE 132    // Beta row stride in workspace (floats), 16B-aligned rows
#define STDDEV 0.1f

// ---------------------------------------------------------------------------
// Kernel 1: per batch (one 256-thread block): build XtX (129x129), Xty, then
// Gaussian elimination (SPD, no pivoting) + back-substitution -> Beta[129].
// Dynamic LDS layout (floats):
//   sA    [NCOL*LDA]  = 17028   (during tiles: rows 0..63 hold xl tile)
//   yt    [64]
//   Wl    [128]
//   xv    [128]
//   rhs   [NCOL]
//   betaL [NCOL]
// total 17606 floats = 70424 bytes
// ---------------------------------------------------------------------------
#define K1_LDS_FLOATS 17606
#define K1_LDS_BYTES  (K1_LDS_FLOATS * 4)

__global__ __launch_bounds__(256, 2)
void k_fit(const float* __restrict__ x, const float* __restrict__ noise,
           const float* __restrict__ W, const float* __restrict__ bptr,
           float* __restrict__ Beta) {
  extern __shared__ float smem[];
  float* sA    = smem;                    // 17028
  float* yt    = sA + NCOL * LDA;         // 64
  float* Wl    = yt + 64;                 // 128
  float* xv    = Wl + 128;                // 128
  float* rhs   = xv + 128;                // 129
  float* betaL = rhs + NCOL;              // 129

  const int t  = threadIdx.x;
  const int b  = blockIdx.x;
  const int tx = t & 15;
  const int ty = t >> 4;
  const float bscal = bptr[0];

  if (t < 128) { Wl[t] = W[t]; xv[t] = x[(size_t)b * ND + t]; }

  float acc[8][8];
#pragma unroll
  for (int i = 0; i < 8; ++i)
#pragma unroll
    for (int j = 0; j < 8; ++j) acc[i][j] = 0.f;
  float col_acc = 0.f;   // column sums (border row/col of XtX), index t
  float xty_acc = 0.f;   // Xty, index t

  const float* nb = noise + (size_t)b * (NS * ND);

  for (int s0 = 0; s0 < NS; s0 += 64) {
    __syncthreads();  // tile buffer free (and Wl/xv visible on first iter)
    // --- load tile: 64 samples x 128 feats -> xl = x + 0.1*noise ---
    {
      const float4* src = (const float4*)(nb + (size_t)s0 * ND);
      for (int it = 0; it < 8; ++it) {
        int idx = t + it * 256;     // 0..2047 float4s
        int s   = idx >> 5;         // sample in tile
        int d4  = idx & 31;         // float4 within row
        float4 nv = src[idx];
        float4 xl;
        xl.x = xv[d4 * 4 + 0] + STDDEV * nv.x;
        xl.y = xv[d4 * 4 + 1] + STDDEV * nv.y;
        xl.z = xv[d4 * 4 + 2] + STDDEV * nv.z;
        xl.w = xv[d4 * 4 + 3] + STDDEV * nv.w;
        *(float4*)&sA[s * LDA + d4 * 4] = xl;
      }
      if (t < 64) sA[t * LDA + ND] = 1.0f;  // ones column
    }
    __syncthreads();
    // --- y for tile: 4 threads per sample, dot(xl_feat, W)+b -> sigmoid ---
    {
      int sl = t >> 2, p = t & 3;
      float acw = 0.f;
      const float* row  = &sA[sl * LDA + p * 32];
      const float* wrow = &Wl[p * 32];
#pragma unroll
      for (int d = 0; d < 32; d += 4) {
        float4 a = *(const float4*)&row[d];
        float4 w = *(const float4*)&wrow[d];
        acw += a.x * w.x + a.y * w.y + a.z * w.z + a.w * w.w;
      }
      acw += __shfl_xor(acw, 1);
      acw += __shfl_xor(acw, 2);
      if (p == 0) yt[sl] = 1.f / (1.f + expf(-(acw + bscal)));
    }
    __syncthreads();
    // --- border (col sums) + Xty ---
    if (t < NCOL) {
      for (int s = 0; s < 64; ++s) {
        float v = sA[s * LDA + t];
        col_acc += v;
        xty_acc += yt[s] * v;
      }
    }
    // --- 8x8 register-blocked XtX core (i,j in 0..127) ---
    {
      const float* pa = &sA[ty * 8];
      const float* pb = &sA[tx * 8];
      for (int s = 0; s < 64; ++s) {
        float4 a0 = *(const float4*)&pa[s * LDA];
        float4 a1 = *(const float4*)&pa[s * LDA + 4];
        float4 b0 = *(const float4*)&pb[s * LDA];
        float4 b1 = *(const float4*)&pb[s * LDA + 4];
        float av[8] = {a0.x, a0.y, a0.z, a0.w, a1.x, a1.y, a1.z, a1.w};
        float bv[8] = {b0.x, b0.y, b0.z, b0.w, b1.x, b1.y, b1.z, b1.w};
#pragma unroll
        for (int i = 0; i < 8; ++i)
#pragma unroll
          for (int j = 0; j < 8; ++j) acc[i][j] += av[i] * bv[j];
      }
    }
  }
  __syncthreads();  // all tile reads done; sA now becomes XtX storage
  // --- assemble XtX in LDS ---
#pragma unroll
  for (int i = 0; i < 8; ++i) {
    *(float4*)&sA[(ty * 8 + i) * LDA + tx * 8] =
        make_float4(acc[i][0], acc[i][1], acc[i][2], acc[i][3]);
    *(float4*)&sA[(ty * 8 + i) * LDA + tx * 8 + 4] =
        make_float4(acc[i][4], acc[i][5], acc[i][6], acc[i][7]);
  }
  if (t < NCOL) {
    sA[ND * LDA + t] = col_acc;   // row 128 (ones row); corner = 256
    sA[t * LDA + ND] = col_acc;   // col 128
    rhs[t] = xty_acc;             // t==128: sum(y)
  }
  __syncthreads();
  // --- Gaussian elimination, no pivoting (SPD) ---
  for (int k = 0; k < NCOL - 1; ++k) {
    float pinv = 1.0f / sA[k * LDA + k];
    const float* rowk = &sA[k * LDA];
    for (int i = k + 1 + ty; i < NCOL; i += 16) {
      float m = sA[i * LDA + k] * pinv;
      float* rowi = &sA[i * LDA];
      for (int j = k + 1 + tx; j < NCOL; j += 16) rowi[j] -= m * rowk[j];
      if (tx == 0) rhs[i] -= m * rhs[k];
    }
    __syncthreads();
  }
  // --- back substitution (wave 0 only) ---
  if (t < 64) {
    for (int i = NCOL - 1; i >= 0; --i) {
      float s = 0.f;
      const float* rowi = &sA[i * LDA];
      for (int j = i + 1 + t; j < NCOL; j += 64) s += rowi[j] * betaL[j];
#pragma unroll
      for (int off = 32; off >= 1; off >>= 1) s += __shfl_xor(s, off);
      if (t == 0) betaL[i] = (rhs[i] - s) / sA[i * LDA + i];
      asm volatile("s_waitcnt lgkmcnt(0)" ::: "memory");
      __builtin_amdgcn_wave_barrier();
    }
    float* Bo = Beta + (size_t)b * BSTRIDE;
    Bo[t] = betaL[t];
    Bo[t + 64] = betaL[t + 64];
    if (t == 0) Bo[128] = betaL[128];
  }
}

// ---------------------------------------------------------------------------
// Kernel 2: BCE over all (b,s). 32 lanes per sample, 8 samples per group.
// partial[block] = sum of bce over the block's samples.
// ---------------------------------------------------------------------------
__device__ inline float logsig(float v) {
  // stable log(sigmoid(v))
  if (v >= 0.f) return -log1pf(expf(-v));
  return v - log1pf(expf(v));
}

__global__ __launch_bounds__(256)
void k_bce(const float* __restrict__ x, const float* __restrict__ noise,
           const float* __restrict__ W, const float* __restrict__ bptr,
           const float* __restrict__ Beta, float* __restrict__ partial) {
  const int t    = threadIdx.x;
  const int lane = t & 31;
  const size_t grp = ((size_t)blockIdx.x * 256 + t) >> 5;
  const float bscal = bptr[0];
  const float4 w4 = *((const float4*)W + lane);

  float lsum = 0.f;
  size_t base = grp * 8;
  for (int it = 0; it < 8; ++it) {
    size_t idx = base + it;          // flat sample id, < NB*NS
    int bb = (int)(idx >> 8);        // batch
    float4 n4 = *((const float4*)noise + idx * 32 + lane);
    float4 x4 = *((const float4*)x + (size_t)bb * 32 + lane);
    float4 p4 = *((const float4*)(Beta + (size_t)bb * BSTRIDE) + lane);
    float4 xl;
    xl.x = x4.x + STDDEV * n4.x;
    xl.y = x4.y + STDDEV * n4.y;
    xl.z = x4.z + STDDEV * n4.z;
    xl.w = x4.w + STDDEV * n4.w;
    float aw = xl.x * w4.x + xl.y * w4.y + xl.z * w4.z + xl.w * w4.w;
    float ab = xl.x * p4.x + xl.y * p4.y + xl.z * p4.z + xl.w * p4.w;
#pragma unroll
    for (int off = 16; off >= 1; off >>= 1) {
      aw += __shfl_xor(aw, off);
      ab += __shfl_xor(ab, off);
    }
    if (lane == 0) {
      float y    = 1.f / (1.f + expf(-(aw + bscal)));
      float ylin = ab + Beta[(size_t)bb * BSTRIDE + 128];
      float lp   = logsig(ylin);
      float lmp  = logsig(-ylin);
      lsum += -(y * lp + (1.f - y) * lmp);
    }
  }
  // lanes 0 and 32 hold group sums
  lsum += __shfl_xor(lsum, 32);
  __shared__ float red[4];
  if ((t & 63) == 0) red[t >> 6] = lsum;
  __syncthreads();
  if (t == 0) partial[blockIdx.x] = red[0] + red[1] + red[2] + red[3];
}

// ---------------------------------------------------------------------------
// Kernel 3: reduce partials -> mean
// ---------------------------------------------------------------------------
__global__ void k_final(const float* __restrict__ partial, float* __restrict__ out,
                        int n, float inv) {
  __shared__ float red[256];
  float s = 0.f;
  for (int i = threadIdx.x; i < n; i += 256) s += partial[i];
  red[threadIdx.x] = s;
  __syncthreads();
  for (int k = 128; k > 0; k >>= 1) {
    if (threadIdx.x < k) red[threadIdx.x] += red[threadIdx.x + k];
    __syncthreads();
  }
  if (threadIdx.x == 0) out[0] = red[0] * inv;
}

extern "C" void kernel_launch(void* const* d_in, const int* in_sizes, int n_in,
                              void* d_out, int out_size, void* d_ws, size_t ws_size,
                              hipStream_t stream) {
  const float* x     = (const float*)d_in[0];
  const float* noise = (const float*)d_in[1];
  const float* W     = (const float*)d_in[2];
  const float* bptr  = (const float*)d_in[3];
  float* out = (float*)d_out;

  // ws layout: Beta [NB][BSTRIDE] f32, then partials
  float* Beta = (float*)d_ws;
  const size_t beta_bytes = (size_t)NB * BSTRIDE * sizeof(float);
  float* partial = (float*)((char*)d_ws + ((beta_bytes + 255) & ~(size_t)255));

  const int nblk2 = (NB * NS) / (8 * 8);  // 8 samples/group, 8 groups/block = 8192

  static bool attr_set = false;
  if (!attr_set) {
    (void)hipFuncSetAttribute((const void*)k_fit,
                              hipFuncAttributeMaxDynamicSharedMemorySize,
                              K1_LDS_BYTES);
    attr_set = true;
  }

  k_fit<<<NB, 256, K1_LDS_BYTES, stream>>>(x, noise, W, bptr, Beta);
  k_bce<<<nblk2, 256, 0, stream>>>(x, noise, W, bptr, Beta, partial);
  k_final<<<1, 256, 0, stream>>>(partial, out, nblk2, 1.0f / (float)(NB * NS));
}